// Round 7
// baseline (811.460 us; speedup 1.0000x reference)
//
#include <hip/hip_runtime.h>

#define NB 4
#define CIN 256
#define CO 512
#define HH 128
#define WW 128
#define PP (HH*WW)     // 16384
#define HO 64
#define TT (HO*HO)     // 4096
#define MTOT (NB*TT)   // 16384 rows
#define EPSL 1e-5f

typedef unsigned short u16;
typedef unsigned int   u32;
typedef __attribute__((ext_vector_type(8))) short short8;
typedef __attribute__((ext_vector_type(4))) float f32x4;

__device__ __forceinline__ float b2f(u16 u){
  union{float f; u32 i;} x; x.i = ((u32)u)<<16; return x.f;
}
__device__ __forceinline__ u16 f2b(float f){
  union{float f; u32 i;} x; x.f = f;
  u32 r = x.i + 0x7fffu + ((x.i>>16)&1u);   // RNE
  return (u16)(r>>16);
}

__device__ __forceinline__ void gl16(const u16* g, u16* l){
  __builtin_amdgcn_global_load_lds((const __attribute__((address_space(1))) void*)g,
                                   (__attribute__((address_space(3))) void*)l, 16, 0, 0);
}

// ---------------------------------------------------------------------------
// Fused split-bf16 GEMM + channel-LN + residual, full-row tile.
// BM=64, BN=512(=CO), BK=32, 512 thr = 8 waves, wave-tile 64x64.
// XS[row][col] = (MODE? rec(XS) : 0) + LN_row( sum_k A[row][k]*B[col][k]+bias[col] )
// A,B split hi/lo bf16 (3 MFMAs). Double-buffered LDS, gl_lds, vmcnt(9).
// ---------------------------------------------------------------------------
template<int K, int MODE>
__global__ __launch_bounds__(512) void gemm_ln64(
    const u16* __restrict__ Ah, const u16* __restrict__ Al,   // (MTOT, K)
    const u16* __restrict__ Bh, const u16* __restrict__ Bl,   // (CO, K)
    const float* __restrict__ bias,
    const float* __restrict__ g, const float* __restrict__ be,
    u16* __restrict__ XSh, u16* __restrict__ XSl)             // (MTOT, CO)
{
  const int r0 = blockIdx.x*64;
  const int tid = threadIdx.x, wid = tid>>6, lane = tid&63;
  const int lr = lane&15, lg = lane>>4;

  __shared__ u16 smAh[2][2048];
  __shared__ u16 smAl[2][2048];
  __shared__ u16 smBh[2][16384];
  __shared__ u16 smBl[2][16384];
  __shared__ float red[2][64][8];

  const size_t abase = (size_t)r0*K;
  f32x4 acc[4][4] = {};   // [mf][nf]

  // staging map: A: 1 chunk/thread (tid<256 -> hi, else lo). B: 4 hi + 4 lo.
  const int ach = tid & 255;
  const int ar = ach>>2, ac = ach&3;
  const size_t agoff = (size_t)ar*K + (size_t)((ac ^ ((ar>>1)&3))*8);
  const u16* Aptr = (tid < 256 ? Ah : Al);
  int brow[4]; size_t bgoff[4];
  #pragma unroll
  for (int p=0;p<4;++p){
    int cb = p*512 + tid;
    brow[p] = cb>>2; int bc = cb&3;
    bgoff[p] = (size_t)brow[p]*K + (size_t)((bc ^ ((brow[p]>>1)&3))*8);
  }

  const int NS = K/32;
  #pragma unroll 1
  for (int s = 0; s < NS; ++s) {
    if (s == 0) {
      u16* a_d = (tid<256 ? smAh[0] : smAl[0]);
      gl16(Aptr+abase+agoff, a_d + ach*8);
      #pragma unroll
      for (int p=0;p<4;++p){
        int cb = p*512 + tid;
        gl16(Bh+bgoff[p], smBh[0] + cb*8);
        gl16(Bl+bgoff[p], smBl[0] + cb*8);
      }
    }
    if (s+1 < NS) {
      const int nb = (s+1)&1;
      const size_t ko = (size_t)(s+1)*32;
      u16* a_d = (tid<256 ? smAh[nb] : smAl[nb]);
      gl16(Aptr+abase+agoff+ko, a_d + ach*8);
      #pragma unroll
      for (int p=0;p<4;++p){
        int cb = p*512 + tid;
        gl16(Bh+bgoff[p]+ko, smBh[nb] + cb*8);
        gl16(Bl+bgoff[p]+ko, smBl[nb] + cb*8);
      }
      asm volatile("s_waitcnt vmcnt(9)" ::: "memory");
    } else {
      asm volatile("s_waitcnt vmcnt(0)" ::: "memory");
    }
    __builtin_amdgcn_s_barrier();
    __builtin_amdgcn_sched_barrier(0);
    {
      const int bs = s&1;
      short8 bhf[4], blf[4];
      #pragma unroll
      for (int nf=0; nf<4; ++nf) {
        int row = wid*64 + nf*16 + lr;
        int off = row*32 + ((lg ^ ((row>>1)&3))<<3);
        bhf[nf] = *(const short8*)(smBh[bs]+off);
        blf[nf] = *(const short8*)(smBl[bs]+off);
      }
      #pragma unroll
      for (int mf=0; mf<4; ++mf) {
        int row = mf*16 + lr;
        int off = row*32 + ((lg ^ ((row>>1)&3))<<3);
        short8 ah = *(const short8*)(smAh[bs]+off);
        short8 al = *(const short8*)(smAl[bs]+off);
        #pragma unroll
        for (int nf=0; nf<4; ++nf) {
          acc[mf][nf] = __builtin_amdgcn_mfma_f32_16x16x32_bf16(ah, bhf[nf], acc[mf][nf],0,0,0);
          acc[mf][nf] = __builtin_amdgcn_mfma_f32_16x16x32_bf16(ah, blf[nf], acc[mf][nf],0,0,0);
          acc[mf][nf] = __builtin_amdgcn_mfma_f32_16x16x32_bf16(al, bhf[nf], acc[mf][nf],0,0,0);
        }
      }
    }
    __builtin_amdgcn_sched_barrier(0);
    __builtin_amdgcn_s_barrier();
  }
  __builtin_amdgcn_sched_barrier(0);

  // ---- epilogue: bias, row stats, LN, residual, split store ----
  float s1[4][4] = {}, s2v[4][4] = {};
  #pragma unroll
  for (int nf=0; nf<4; ++nf) {
    float bs = bias[wid*64 + nf*16 + lr];
    #pragma unroll
    for (int mf=0; mf<4; ++mf)
      #pragma unroll
      for (int j=0; j<4; ++j) {
        float v = acc[mf][nf][j] + bs;
        acc[mf][nf][j] = v;
        s1[mf][j] += v; s2v[mf][j] += v*v;
      }
  }
  #pragma unroll
  for (int m=1; m<=8; m<<=1)
    #pragma unroll
    for (int mf=0; mf<4; ++mf)
      #pragma unroll
      for (int j=0; j<4; ++j) {
        s1[mf][j]  += __shfl_xor(s1[mf][j],  m, 64);
        s2v[mf][j] += __shfl_xor(s2v[mf][j], m, 64);
      }
  if (lr == 0) {
    #pragma unroll
    for (int mf=0; mf<4; ++mf)
      #pragma unroll
      for (int j=0; j<4; ++j) {
        int row = mf*16 + lg*4 + j;
        red[0][row][wid] = s1[mf][j];
        red[1][row][wid] = s2v[mf][j];
      }
  }
  __syncthreads();
  float mu[4][4], rs[4][4];
  #pragma unroll
  for (int mf=0; mf<4; ++mf)
    #pragma unroll
    for (int j=0; j<4; ++j) {
      int row = mf*16 + lg*4 + j;
      float S = 0.f, S2 = 0.f;
      #pragma unroll
      for (int w=0; w<8; ++w) { S += red[0][row][w]; S2 += red[1][row][w]; }
      float m_ = S*(1.f/CO);
      mu[mf][j] = m_;
      rs[mf][j] = rsqrtf(S2*(1.f/CO) - m_*m_ + EPSL);
    }
  #pragma unroll
  for (int nf=0; nf<4; ++nf) {
    int col = wid*64 + nf*16 + lr;
    float gg = g[col], bb = be[col];
    #pragma unroll
    for (int mf=0; mf<4; ++mf)
      #pragma unroll
      for (int j=0; j<4; ++j) {
        size_t grow = (size_t)r0 + mf*16 + lg*4 + j;
        size_t xi = grow*CO + col;
        float r = gg*(acc[mf][nf][j]-mu[mf][j])*rs[mf][j] + bb;
        float nv = MODE ? (b2f(XSh[xi]) + b2f(XSl[xi]) + r) : r;
        u16 h = f2b(nv);
        XSh[xi] = h;
        XSl[xi] = f2b(nv - b2f(h));
      }
  }
}

// ---------------------------------------------------------------------------
// Generic split-bf16 MFMA GEMM, 128x128 tile, 4 waves, BK=32 (qk only).
// f32 out, bias per-row. LDS chunk swizzle c' = c ^ ((row>>1)&3).
// ---------------------------------------------------------------------------
template<int K>
__global__ __launch_bounds__(256) void gemm_t(
    const u16* __restrict__ Ah, const u16* __restrict__ Al, size_t aBS,
    const u16* __restrict__ Bh, const u16* __restrict__ Bl, size_t bBS,
    const float* __restrict__ bias,
    float* __restrict__ OUTf, size_t oBS, int oLd)
{
  const int z = blockIdx.z;
  const int r0 = blockIdx.x*128, c0 = blockIdx.y*128;
  const int tid = threadIdx.x, wid = tid>>6, lane = tid&63;
  const int wm = wid>>1, wn = wid&1, lr = lane&15, lg = lane>>4;

  extern __shared__ u16 sm[];

  const size_t abase = (size_t)z*aBS + (size_t)r0*K;
  const size_t bbase = (size_t)z*bBS + (size_t)c0*K;

  f32x4 acc[4][4] = {};

  const int q0 = tid, q1 = tid+256;
  const int r_0 = q0>>2, c_0 = q0&3;
  const int r_1 = q1>>2, c_1 = q1&3;
  const size_t go0 = (size_t)r_0*K + (size_t)((c_0 ^ ((r_0>>1)&3))*8);
  const size_t go1 = (size_t)r_1*K + (size_t)((c_1 ^ ((r_1>>1)&3))*8);

  const int NS = K/32;
  #pragma unroll 1
  for (int s = 0; s < NS; ++s) {
    if (s == 0) {
      u16* buf = sm;
      gl16(Ah+abase+go0, buf+q0*8);        gl16(Ah+abase+go1, buf+q1*8);
      gl16(Al+abase+go0, buf+4096+q0*8);   gl16(Al+abase+go1, buf+4096+q1*8);
      gl16(Bh+bbase+go0, buf+8192+q0*8);   gl16(Bh+bbase+go1, buf+8192+q1*8);
      gl16(Bl+bbase+go0, buf+12288+q0*8);  gl16(Bl+bbase+go1, buf+12288+q1*8);
    }
    if (s+1 < NS) {
      u16* buf = sm + ((s+1)&1)*16384;
      const size_t ko = (size_t)(s+1)*32;
      gl16(Ah+abase+go0+ko, buf+q0*8);        gl16(Ah+abase+go1+ko, buf+q1*8);
      gl16(Al+abase+go0+ko, buf+4096+q0*8);   gl16(Al+abase+go1+ko, buf+4096+q1*8);
      gl16(Bh+bbase+go0+ko, buf+8192+q0*8);   gl16(Bh+bbase+go1+ko, buf+8192+q1*8);
      gl16(Bl+bbase+go0+ko, buf+12288+q0*8);  gl16(Bl+bbase+go1+ko, buf+12288+q1*8);
      asm volatile("s_waitcnt vmcnt(8)" ::: "memory");
    } else {
      asm volatile("s_waitcnt vmcnt(0)" ::: "memory");
    }
    __builtin_amdgcn_s_barrier();
    __builtin_amdgcn_sched_barrier(0);
    {
      const u16* buf = sm + (s&1)*16384;
      const u16* Ax = buf, *Ay = buf+4096, *Bx = buf+8192, *By = buf+12288;
      short8 bh[4], bl[4];
      #pragma unroll
      for (int nf=0; nf<4; ++nf) {
        int row = wn*64 + nf*16 + lr;
        int off = row*32 + ((lg ^ ((row>>1)&3))<<3);
        bh[nf] = *(const short8*)(Bx+off);
        bl[nf] = *(const short8*)(By+off);
      }
      #pragma unroll
      for (int mf=0; mf<4; ++mf) {
        int row = wm*64 + mf*16 + lr;
        int off = row*32 + ((lg ^ ((row>>1)&3))<<3);
        short8 ah = *(const short8*)(Ax+off);
        short8 al = *(const short8*)(Ay+off);
        #pragma unroll
        for (int nf=0; nf<4; ++nf) {
          acc[mf][nf] = __builtin_amdgcn_mfma_f32_16x16x32_bf16(ah, bh[nf], acc[mf][nf],0,0,0);
          acc[mf][nf] = __builtin_amdgcn_mfma_f32_16x16x32_bf16(ah, bl[nf], acc[mf][nf],0,0,0);
          acc[mf][nf] = __builtin_amdgcn_mfma_f32_16x16x32_bf16(al, bh[nf], acc[mf][nf],0,0,0);
        }
      }
    }
    __builtin_amdgcn_sched_barrier(0);
    __builtin_amdgcn_s_barrier();
  }
  __builtin_amdgcn_sched_barrier(0);

  #pragma unroll
  for (int mf=0; mf<4; ++mf) {
    #pragma unroll
    for (int nf=0; nf<4; ++nf) {
      int col = c0 + wn*64 + nf*16 + lr;
      #pragma unroll
      for (int j=0; j<4; ++j) {
        int row = r0 + wm*64 + mf*16 + lg*4 + j;
        OUTf[(size_t)z*oBS + (size_t)row*oLd + col] = acc[mf][nf][j] + bias[row];
      }
    }
  }
}

// ---------------------------------------------------------------------------
// Attention: logits from QK (b,i,t f32) and x_in (f32), softmax over the 4
// window positions, p-weighted pooling -> XP pair (b,t,i). 64 t x 4 i-groups.
// ---------------------------------------------------------------------------
__global__ __launch_bounds__(256) void att_xp(
    const float* __restrict__ qk, const float* __restrict__ x_in,
    u16* __restrict__ XPh, u16* __restrict__ XPl)
{
  const int b = blockIdx.y;
  const int tl = threadIdx.x & 63, cg = threadIdx.x >> 6;
  const int t = blockIdx.x*64 + tl;
  const int ho = t >> 6, wo = t & 63;
  const size_t p00 = (size_t)(2*ho)*WW + 2*wo;

  float a0=0.f, a1=0.f, a2=0.f, a3=0.f;
  for (int i = cg*64; i < cg*64 + 64; ++i) {
    float qv = qk[((size_t)b*CIN + i)*TT + t];
    const float* xr = x_in + ((size_t)b*CIN + i)*PP + p00;
    float2 x01 = *(const float2*)xr;
    float2 x23 = *(const float2*)(xr + WW);
    a0 += qv*x01.x; a1 += qv*x01.y; a2 += qv*x23.x; a3 += qv*x23.y;
  }
  __shared__ float attp[4][64][4];
  attp[cg][tl][0] = a0; attp[cg][tl][1] = a1;
  attp[cg][tl][2] = a2; attp[cg][tl][3] = a3;
  __syncthreads();
  a0 = attp[0][tl][0] + attp[1][tl][0] + attp[2][tl][0] + attp[3][tl][0];
  a1 = attp[0][tl][1] + attp[1][tl][1] + attp[2][tl][1] + attp[3][tl][1];
  a2 = attp[0][tl][2] + attp[1][tl][2] + attp[2][tl][2] + attp[3][tl][2];
  a3 = attp[0][tl][3] + attp[1][tl][3] + attp[2][tl][3] + attp[3][tl][3];
  float m = fmaxf(fmaxf(a0,a1), fmaxf(a2,a3));
  float ee0 = __expf(a0-m), ee1 = __expf(a1-m), ee2 = __expf(a2-m), ee3 = __expf(a3-m);
  float inv = 1.f/(ee0+ee1+ee2+ee3);
  float p0 = ee0*inv, p1 = ee1*inv, p2 = ee2*inv, p3 = ee3*inv;

  for (int ib = 0; ib < 64; ib += 8) {
    short8 oh, ol;
    #pragma unroll
    for (int e = 0; e < 8; ++e) {
      int i = cg*64 + ib + e;
      const float* xr = x_in + ((size_t)b*CIN + i)*PP + p00;
      float2 x01 = *(const float2*)xr;
      float2 x23 = *(const float2*)(xr + WW);
      float u = p0*x01.x + p1*x01.y + p2*x23.x + p3*x23.y;
      u16 h = f2b(u); oh[e] = (short)h; ol[e] = (short)f2b(u - b2f(h));
    }
    size_t o = ((size_t)b*TT + t)*CIN + cg*64 + ib;
    *(short8*)(XPh + o) = oh;
    *(short8*)(XPl + o) = ol;
  }
}

// ---------------------------------------------------------------------------
// Build XC: XC[b][t][w*256+i] = split(x_in window pixels).
// ---------------------------------------------------------------------------
__global__ __launch_bounds__(256) void xc_build(
    const float* __restrict__ x_in, u16* __restrict__ XCh, u16* __restrict__ XCl)
{
  const int ho = blockIdx.x, iblk = blockIdx.y, b = blockIdx.z;
  const int tid = threadIdx.x;
  __shared__ float Ls[32][256];
  {
    const int ii = tid >> 3, q = tid & 7;
    const float4* src = (const float4*)(x_in + ((size_t)(b*CIN + iblk*32 + ii)*PP + (size_t)ho*256));
    #pragma unroll
    for (int p = 0; p < 8; ++p) {
      float4 v = src[q + p*8];
      *(float4*)&Ls[ii][(q + p*8)*4] = v;
    }
  }
  __syncthreads();
  {
    const int wo = tid >> 2, w = tid & 3;
    const int colbase = (w>>1)*128 + 2*wo + (w&1);
    u16 hb[32], lb[32];
    #pragma unroll
    for (int ii = 0; ii < 32; ++ii) {
      float v = Ls[ii][colbase];
      u16 h = f2b(v); hb[ii] = h; lb[ii] = f2b(v - b2f(h));
    }
    size_t t = (size_t)b*TT + ho*64 + wo;
    size_t dst = t*1024 + (size_t)w*256 + iblk*32;
    #pragma unroll
    for (int c = 0; c < 4; ++c) {
      short8 hv, lv;
      #pragma unroll
      for (int e = 0; e < 8; ++e) { hv[e] = (short)hb[c*8+e]; lv[e] = (short)lb[c*8+e]; }
      *(short8*)(XCh + dst + c*8) = hv;
      *(short8*)(XCl + dst + c*8) = lv;
    }
  }
}

// ---------------------------------------------------------------------------
// Final: d_out[b][c][t] = rec(XS[b][t][c])
// ---------------------------------------------------------------------------
__global__ __launch_bounds__(256) void out_transpose(
    const u16* __restrict__ XSh, const u16* __restrict__ XSl, float* __restrict__ xout)
{
  const int b = blockIdx.z, c0 = blockIdx.y*64, t0l = blockIdx.x*64;
  const int tid = threadIdx.x;
  __shared__ float Ts[64][68];
  #pragma unroll
  for (int p = 0; p < 2; ++p) {
    int idx = tid + p*256;
    int row = idx >> 3, ko = (idx & 7)*8;
    size_t off = ((size_t)b*TT + t0l + row)*CO + c0 + ko;
    short8 h8 = *(const short8*)(XSh + off);
    short8 l8 = *(const short8*)(XSl + off);
    #pragma unroll
    for (int e = 0; e < 8; ++e)
      Ts[ko + e][row] = b2f((u16)h8[e]) + b2f((u16)l8[e]);
  }
  __syncthreads();
  const int cl = tid >> 2, tq = tid & 3;
  #pragma unroll
  for (int p = 0; p < 4; ++p) {
    int t4 = (tq + p*4)*4;
    float4 v = *(const float4*)&Ts[cl][t4];
    *(float4*)(xout + ((size_t)b*CO + c0 + cl)*TT + t0l + t4) = v;
  }
}

// ---------------------------------------------------------------------------
// Prep kernels
// ---------------------------------------------------------------------------
__global__ void split_pack(const float* __restrict__ src, u16* __restrict__ h,
                           u16* __restrict__ l, int n){
  int i = blockIdx.x*256 + threadIdx.x;
  if (i < n) { float v = src[i]; u16 hh = f2b(v); h[i]=hh; l[i]=f2b(v - b2f(hh)); }
}

__global__ void conv_pack(const float* __restrict__ cw, u16* __restrict__ h,
                          u16* __restrict__ l){
  int e = blockIdx.x*256 + threadIdx.x;
  int o = e >> 10, r = e & 1023, w = r >> 8, i = r & 255;
  float v = cw[o*1024 + i*4 + w];
  u16 hh = f2b(v); h[e]=hh; l[e]=f2b(v - b2f(hh));
}

// Mt[i][j] = sum_f k_w[f][i] * q_w[f][j]   (256 x 512), split-pair output
__global__ __launch_bounds__(256) void gemm_tn(
    const float* __restrict__ A, const float* __restrict__ B,
    u16* __restrict__ MtH, u16* __restrict__ MtL)
{
  const int i0 = blockIdx.y*64, j0 = blockIdx.x*64;
  const int tid = threadIdx.x, tx = tid & 15, ty = tid >> 4;
  __shared__ float As[16][64];
  __shared__ float Bs[16][64];
  float acc[4][4] = {};
  for (int f0 = 0; f0 < CO; f0 += 16) {
    int tt = tid & 63, kkb = tid >> 6;
    #pragma unroll
    for (int s = 0; s < 4; ++s) {
      As[kkb+s*4][tt] = A[(size_t)(f0+kkb+s*4)*CIN + i0 + tt];
      Bs[kkb+s*4][tt] = B[(size_t)(f0+kkb+s*4)*CO  + j0 + tt];
    }
    __syncthreads();
    #pragma unroll
    for (int kk = 0; kk < 16; ++kk) {
      float4 av = *reinterpret_cast<const float4*>(&As[kk][ty*4]);
      float4 bv = *reinterpret_cast<const float4*>(&Bs[kk][tx*4]);
      float a[4] = {av.x,av.y,av.z,av.w}, c[4] = {bv.x,bv.y,bv.z,bv.w};
      #pragma unroll
      for (int j = 0; j < 4; ++j)
        #pragma unroll
        for (int i = 0; i < 4; ++i) acc[j][i] += a[j]*c[i];
    }
    __syncthreads();
  }
  #pragma unroll
  for (int j = 0; j < 4; ++j) {
    #pragma unroll
    for (int i = 0; i < 4; ++i) {
      float v = acc[j][i];
      size_t idx = (size_t)(i0+ty*4+j)*CO + j0 + tx*4 + i;
      u16 h = f2b(v);
      MtH[idx] = h; MtL[idx] = f2b(v - b2f(h));
    }
  }
}

__global__ void qbk_kernel(const float* __restrict__ q_b,
                           const float* __restrict__ k_w, float* __restrict__ qbk)
{
  int i = threadIdx.x;
  float s = 0.f;
  for (int f = 0; f < CO; ++f) s += q_b[f]*k_w[(size_t)f*CIN + i];
  qbk[i] = s;
}

// ---------------------------------------------------------------------------
extern "C" void kernel_launch(void* const* d_in, const int* in_sizes, int n_in,
                              void* d_out, int out_size, void* d_ws, size_t ws_size,
                              hipStream_t stream) {
  const float* x_in   = (const float*)d_in[0];
  const float* conv_w = (const float*)d_in[1];
  const float* conv_b = (const float*)d_in[2];
  const float* k_w    = (const float*)d_in[3];
  const float* q_w    = (const float*)d_in[5];
  const float* q_b    = (const float*)d_in[6];
  const float* v_w    = (const float*)d_in[7];
  const float* v_b    = (const float*)d_in[8];
  const float* mlp_w  = (const float*)d_in[9];
  const float* mlp_b  = (const float*)d_in[10];
  const float* lnc_g  = (const float*)d_in[11];
  const float* lnc_b  = (const float*)d_in[12];
  const float* lnv_g  = (const float*)d_in[13];
  const float* lnv_b  = (const float*)d_in[14];
  const float* lnm_g  = (const float*)d_in[15];
  const float* lnm_b  = (const float*)d_in[16];
  float* x_out = (float*)d_out;

  char* ws = (char*)d_ws;
  const size_t MBy = (size_t)1<<20;
  u16* XCh = (u16*)(ws + 0*MBy);           // 32 MiB (16384 x 1024)
  u16* XCl = (u16*)(ws + 32*MBy);          // 32 MiB
  u16* XSh = (u16*)(ws + 64*MBy);          // 16 MiB (16384 x 512)
  u16* XSl = (u16*)(ws + 80*MBy);          // 16 MiB
  u16* XPh = (u16*)(ws + 96*MBy);          // 8 MiB (16384 x 256)
  u16* XPl = (u16*)(ws + 104*MBy);         // 8 MiB
  float* QK = (float*)(ws + 112*MBy);      // 16 MiB (b,i,t) f32
  u16* WCh = (u16*)(ws + 128*MBy);         // 1 MiB
  u16* WCl = (u16*)(ws + 129*MBy);         // 1 MiB
  u16* MWh = (u16*)(ws + 130*MBy);         // 0.5 MiB
  u16* MWl = (u16*)(ws + 130*MBy + 512*1024);
  u16* VWh = (u16*)(ws + 131*MBy);         // 0.25 MiB
  u16* VWl = (u16*)(ws + 131*MBy + 256*1024);
  u16* MtH = (u16*)(ws + 131*MBy + 512*1024);
  u16* MtL = (u16*)(ws + 131*MBy + 768*1024);
  float* QBK = (float*)(ws + 132*MBy);     // 1 KB

  // --- prep ---
  conv_pack<<<2048, 256, 0, stream>>>(conv_w, WCh, WCl);
  split_pack<<<512, 256, 0, stream>>>(v_w, VWh, VWl, CO*CIN);
  split_pack<<<1024, 256, 0, stream>>>(mlp_w, MWh, MWl, CO*CO);
  gemm_tn<<<dim3(CO/64, CIN/64), 256, 0, stream>>>(k_w, q_w, MtH, MtL);
  qbk_kernel<<<1, CIN, 0, stream>>>(q_b, k_w, QBK);
  xc_build<<<dim3(HO, 8, NB), 256, 0, stream>>>(x_in, XCh, XCl);

  // --- conv + LN_c fused -> XS ---
  gemm_ln64<1024,0><<<MTOT/64, 512, 0, stream>>>(
      XCh, XCl, WCh, WCl, conv_b, lnc_g, lnc_b, XSh, XSl);

  for (int it = 0; it < 3; ++it) {
    // QK[b][i][t] = Mt[i][:] . x_out[t][:] + QBK[i]
    gemm_t<512><<<dim3(CIN/128, TT/128, NB), 256, 65536, stream>>>(
        MtH, MtL, (size_t)0, XSh, XSl, (size_t)TT*CO, QBK,
        QK, (size_t)CIN*TT, TT);
    att_xp<<<dim3(TT/64, NB), 256, 0, stream>>>(QK, x_in, XPh, XPl);
    // XS += LN(v_w . xp + v_b)
    gemm_ln64<256,1><<<MTOT/64, 512, 0, stream>>>(
        XPh, XPl, VWh, VWl, v_b, lnv_g, lnv_b, XSh, XSl);
    // XS += LN(mlp_w . XS + mlp_b)
    gemm_ln64<512,1><<<MTOT/64, 512, 0, stream>>>(
        XSh, XSl, MWh, MWl, mlp_b, lnm_g, lnm_b, XSh, XSl);
  }

  // --- emit f32 (b, c, t) ---
  out_transpose<<<dim3(TT/64, CO/64, NB), 256, 0, stream>>>(XSh, XSl, x_out);
}